// Round 8
// baseline (658.487 us; speedup 1.0000x reference)
//
#include <hip/hip_runtime.h>
#include <cstddef>
#include <cstdint>

typedef __attribute__((ext_vector_type(4))) float f32x4;
typedef __attribute__((ext_vector_type(8))) short s16x8;
typedef __attribute__((ext_vector_type(4))) unsigned short u16x4;

constexpr int CC = 192, NHEAD = 6, HD = 32, NTOK = 49, IMG = 112, TOTWIN = 4096;
constexpr int MTOK = TOTWIN * NTOK;            // 200704
constexpr int NX   = MTOK * CC;                // 38,535,168
constexpr float QSCALE = 0.17677669529663687f; // 32^-0.5
// fragment-major planes: q/k: [task][qt(4)][lane(64)][8]; v: [task][s(2)][ni(2)][lane][8]
constexpr size_t PLANE_U16 = (size_t)TOTWIN * NHEAD * 4 * 64 * 8; // 50,331,648 u16 each
constexpr int WQ_SLOTS = 6 * 36 * 64;  // 13824
constexpr int WP_SLOTS = 6 * 12 * 64;  // 4608
constexpr int TBL_N    = 6 * 4 * 4096; // 98304  layout [h][cls][kt][qt][lane][r]

__device__ __forceinline__ unsigned short bfh(float f) {
    unsigned u = __float_as_uint(f);
    return (unsigned short)((u + 0x7FFFu + ((u >> 16) & 1u)) >> 16);
}
__device__ __forceinline__ float bff(unsigned short h) {
    return __uint_as_float(((unsigned)h) << 16);
}
#define MFMA_BF16(acc, a, b) \
    (acc) = __builtin_amdgcn_mfma_f32_16x16x32_bf16((a), (b), (acc), 0, 0, 0)

// async 16B global->LDS DMA: per-lane global addr, wave-uniform LDS base + lane*16
__device__ __forceinline__ void gll16(const void* g, void* l) {
    __builtin_amdgcn_global_load_lds((const __attribute__((address_space(1))) unsigned int*)g,
                                     (__attribute__((address_space(3))) unsigned int*)l, 16, 0, 0);
}

// gathered x-row offset (elements): roll(-3,-3) + 7x7 window partition
__device__ __forceinline__ int arow_off_qkv(int m) {
    int win = m / NTOK, tok = m - win * NTOK;
    int b = win >> 8, wib = win & 255;
    int ih = tok / 7, iw = tok - ih * 7;
    int sh = (wib >> 4) * 7 + ih + 3; if (sh >= IMG) sh -= IMG;
    int sw = (wib & 15) * 7 + iw + 3; if (sw >= IMG) sw -= IMG;
    return ((b * IMG + sh) * IMG + sw) * CC;
}

// ---------------- kernel A: split x fp32 -> bf16 hi/lo planes ----------------
__global__ void xsplit(const float* __restrict__ x, unsigned short* __restrict__ xh,
                       unsigned short* __restrict__ xl) {
    const int N4 = NX / 4;
    for (int i = blockIdx.x * blockDim.x + threadIdx.x; i < N4; i += gridDim.x * blockDim.x) {
        float4 v = reinterpret_cast<const float4*>(x)[i];
        float f[4] = {v.x, v.y, v.z, v.w};
        u16x4 hv, lv;
        #pragma unroll
        for (int c = 0; c < 4; ++c) {
            unsigned short h = bfh(f[c]);
            hv[c] = h; lv[c] = bfh(f[c] - bff(h));
        }
        *reinterpret_cast<u16x4*>(xh + (size_t)i * 4) = hv;
        *reinterpret_cast<u16x4*>(xl + (size_t)i * 4) = lv;
    }
}

// ---------------- prep: weight frag-planes (hi/lo) + bias/mask table ----------------
__global__ void prep(const float* __restrict__ wq, const float* __restrict__ wp,
                     const float* __restrict__ rbt,
                     short* __restrict__ wqh, short* __restrict__ wql,
                     short* __restrict__ wph, short* __restrict__ wpl,
                     float* __restrict__ tbl) {
    int i = blockIdx.x * 256 + threadIdx.x;
    if (i < WQ_SLOTS + WP_SLOTS) {
        const float* src; short *dh, *dl; int slot, nfr;
        if (i < WQ_SLOTS) { src = wq; dh = wqh; dl = wql; slot = i; nfr = 36; }
        else              { src = wp; dh = wph; dl = wpl; slot = i - WQ_SLOTS; nfr = 12; }
        int kt = slot / (nfr * 64), rem = slot % (nfr * 64), f = rem >> 6, lane = rem & 63;
        int n = f * 16 + (lane & 15), k = kt * 32 + (lane >> 4) * 8;
        s16x8 hv, lv;
        #pragma unroll
        for (int j = 0; j < 8; ++j) {
            float v = src[n * CC + k + j];
            unsigned short h = bfh(v);
            hv[j] = (short)h; lv[j] = (short)bfh(v - bff(h));
        }
        *reinterpret_cast<s16x8*>(dh + (size_t)slot * 8) = hv;
        *reinterpret_cast<s16x8*>(dl + (size_t)slot * 8) = lv;
    }
    int ti = i - (WQ_SLOTS + WP_SLOTS);
    if (ti >= 0 && ti < TBL_N) {
        // layout: [h][cls][kt(4)][qt(4)][lane(64)][r(4)] so attn loads f32x4 per (kt,qt)
        int h = ti / 16384, rem = ti % 16384, cls = rem >> 12, e = rem & 4095;
        int r = e & 3, lane = (e >> 2) & 63, qt = (e >> 8) & 3, kt = e >> 10;
        int k = kt * 16 + (lane >> 4) * 4 + r, q = qt * 16 + (lane & 15);
        float v;
        if (k >= NTOK) v = -1e30f;           // padded k: excluded from softmax
        else if (q >= NTOK) v = 0.f;         // padded q: rows discarded
        else {
            int qh = q / 7, qw = q % 7, kh = k / 7, kw = k % 7;
            float b = rbt[((qh - kh + 6) * 13 + (qw - kw + 6)) * NHEAD + h];
            int rq = ((cls >> 1) ? (qh < 4 ? 3 : 6) : 0) + ((cls & 1) ? (qw < 4 ? 1 : 2) : 0);
            int rk = ((cls >> 1) ? (kh < 4 ? 3 : 6) : 0) + ((cls & 1) ? (kw < 4 ? 1 : 2) : 0);
            v = (rq != rk) ? b - 100.f : b;
        }
        tbl[ti] = v;
    }
}

// ---------------- bf16x3 GEMM computing C^T, all staging via global_load_lds ----------------
// MODE 0: A = xh/xl (gathered rows), N=576 in 3 nblk; epilogue -> q/k/v frag planes
// MODE 1: A = oh/ol (attn out rows), N=192; epilogue -> d_out via window-reverse+roll (+bias)
template<int MODE>
__global__ __launch_bounds__(256, 2)
void gemm_swapped(const unsigned short* __restrict__ Ah, const unsigned short* __restrict__ Al,
                  const short* __restrict__ Wh, const short* __restrict__ Wl,
                  const float* __restrict__ bias,
                  short* __restrict__ qpl, short* __restrict__ kpl, short* __restrict__ vpl,
                  float* __restrict__ outp) {
    __shared__ s16x8 AhS[512], AlS[512], BhS[768], BlS[768]; // 40 KiB
    int mt, nblk;
    if (MODE == 0) {  // XCD swizzle: co-locate the 3 nblk sharing one A-tile (4704 % 8 == 0)
        int bid = blockIdx.x;
        int virt = (bid & 7) * 588 + (bid >> 3);
        mt = virt / 3; nblk = virt - mt * 3;
    } else { mt = blockIdx.x; nblk = 0; }
    const int t = threadIdx.x, w = t >> 6, lane = t & 63, l15 = lane & 15, lc = lane >> 4;
    const int nfr = (MODE == 0) ? 36 : 12;

    // A fragment-slot layout: AhS[f*64 + l] holds row m = mt*128 + f*16 + (l&15),
    // k-quarter (l>>4). Wave w stages frags f=w and f=w+4 (per-lane global addr).
    const int mA0 = mt * 128 + w * 16 + l15;
    const int mA1 = mA0 + 64;
    const size_t a0 = (size_t)(MODE == 0 ? arow_off_qkv(mA0) : mA0 * CC) + lc * 8;
    const size_t a1 = (size_t)(MODE == 0 ? arow_off_qkv(mA1) : mA1 * CC) + lc * 8;

    f32x4 acc[4][6];
    #pragma unroll
    for (int mi = 0; mi < 4; ++mi)
        #pragma unroll
        for (int ni = 0; ni < 6; ++ni) acc[mi][ni] = (f32x4){0.f, 0.f, 0.f, 0.f};

    const int mh = w >> 1, nh = w & 1;

    for (int kt = 0; kt < 6; ++kt) {
        // A: 4 DMA loads (hi/lo x 2 frags)
        gll16(Ah + a0 + kt * 32, &AhS[w * 64]);
        gll16(Al + a0 + kt * 32, &AlS[w * 64]);
        gll16(Ah + a1 + kt * 32, &AhS[(w + 4) * 64]);
        gll16(Al + a1 + kt * 32, &AlS[(w + 4) * 64]);
        // B: 6 DMA loads (hi/lo x 3 frags per wave)
        #pragma unroll
        for (int u = 0; u < 3; ++u) {
            const size_t gs = ((size_t)((kt * nfr + nblk * 12 + w * 3 + u) * 64) + lane) * 8;
            gll16(Wh + gs, &BhS[(w * 3 + u) * 64]);
            gll16(Wl + gs, &BlS[(w * 3 + u) * 64]);
        }
        __syncthreads();   // compiler drains vmcnt before barrier -> LDS ready

        s16x8 fah[4], fal[4], fbh[6], fbl[6];
        #pragma unroll
        for (int mi = 0; mi < 4; ++mi) {
            fah[mi] = AhS[(mh * 4 + mi) * 64 + lane];
            fal[mi] = AlS[(mh * 4 + mi) * 64 + lane];
        }
        #pragma unroll
        for (int ni = 0; ni < 6; ++ni) {
            fbh[ni] = BhS[(nh * 6 + ni) * 64 + lane];
            fbl[ni] = BlS[(nh * 6 + ni) * 64 + lane];
        }
        // D = W-frag * X-frag  (C^T): term-major for MFMA independence
        #pragma unroll
        for (int mi = 0; mi < 4; ++mi)
            #pragma unroll
            for (int ni = 0; ni < 6; ++ni) MFMA_BF16(acc[mi][ni], fbh[ni], fah[mi]);
        #pragma unroll
        for (int mi = 0; mi < 4; ++mi)
            #pragma unroll
            for (int ni = 0; ni < 6; ++ni) MFMA_BF16(acc[mi][ni], fbh[ni], fal[mi]);
        #pragma unroll
        for (int mi = 0; mi < 4; ++mi)
            #pragma unroll
            for (int ni = 0; ni < 6; ++ni) MFMA_BF16(acc[mi][ni], fbl[ni], fah[mi]);
        __syncthreads();
    }

    // epilogue: C^T D-layout: lane -> C[m = mtile + l15][n = ntile + lc*4 + r]
    #pragma unroll
    for (int mi = 0; mi < 4; ++mi) {
        const int m = mt * 128 + mh * 64 + mi * 16 + l15;
        const int win = m / NTOK, tok = m - win * NTOK;
        if (MODE == 0) {
            const int s = tok >> 5, lcv = (tok >> 3) & 3, jv = tok & 7; // V coords
            const int qt = tok >> 4, l15f = tok & 15;                  // Q/K coords
            #pragma unroll
            for (int ni = 0; ni < 6; ++ni) {
                const int cb = nh * 96 + ni * 16 + lc * 4;     // col-in-192 of r=0
                const int head = cb >> 5, d0 = cb & 31;
                const size_t task = (size_t)(win * NHEAD + head);
                float4 b4 = *reinterpret_cast<const float4*>(bias + nblk * 192 + cb);
                float vv[4] = {acc[mi][ni][0] + b4.x, acc[mi][ni][1] + b4.y,
                               acc[mi][ni][2] + b4.z, acc[mi][ni][3] + b4.w};
                if (nblk == 0) {
                    #pragma unroll
                    for (int r = 0; r < 4; ++r) vv[r] *= QSCALE;
                }
                if (nblk < 2) {
                    short* pl = (nblk == 0) ? qpl : kpl;
                    short* dst = pl + (task * 4 + qt) * 512 + (d0 >> 3) * 128 + l15f * 8 + (d0 & 7);
                    uint2 pk;
                    pk.x = (unsigned)bfh(vv[0]) | ((unsigned)bfh(vv[1]) << 16);
                    pk.y = (unsigned)bfh(vv[2]) | ((unsigned)bfh(vv[3]) << 16);
                    *reinterpret_cast<uint2*>(dst) = pk;
                } else {
                    const int niv = d0 >> 4, l15v0 = d0 & 15;
                    size_t vb = ((task * 2 + s) * 2 + niv) * 512 + lcv * 128 + jv;
                    #pragma unroll
                    for (int r = 0; r < 4; ++r)
                        vpl[vb + (size_t)(l15v0 + r) * 8] = (short)bfh(vv[r]);
                }
            }
        } else {
            const int b = win >> 8, wib = win & 255;
            const int ih = tok / 7, iw = tok - ih * 7;
            int fh = (wib >> 4) * 7 + ih + 3; if (fh >= IMG) fh -= IMG;
            int fw = (wib & 15) * 7 + iw + 3; if (fw >= IMG) fw -= IMG;
            float* orow = outp + ((size_t)((b * IMG + fh) * IMG + fw)) * CC;
            #pragma unroll
            for (int ni = 0; ni < 6; ++ni) {
                const int cb = nh * 96 + ni * 16 + lc * 4;
                float4 b4 = *reinterpret_cast<const float4*>(bias + cb);
                float4 vv = {acc[mi][ni][0] + b4.x, acc[mi][ni][1] + b4.y,
                             acc[mi][ni][2] + b4.z, acc[mi][ni][3] + b4.w};
                *reinterpret_cast<float4*>(orow + cb) = vv;
            }
        }
    }
}

// ---------------- MFMA attention: 1 wave per (window, head) ----------------
// S^T = K*Q^T (lane-local softmax), P regrouped via single-wave LDS, O = P*V
__global__ __launch_bounds__(64)
void attn(const short* __restrict__ qpl, const short* __restrict__ kpl,
          const short* __restrict__ vpl, const float* __restrict__ tbl,
          unsigned short* __restrict__ oh, unsigned short* __restrict__ ol) {
    __shared__ unsigned int FR[2048]; // 8KB: [s][qt][lane][dword]
    const int win = blockIdx.x, h = blockIdx.y;
    const int lane = threadIdx.x, l15 = lane & 15, lc = lane >> 4;
    const size_t tq = (size_t)(win * NHEAD + h) * 2048; // u16

    s16x8 qf[4], kf[4];
    #pragma unroll
    for (int qt = 0; qt < 4; ++qt) {
        qf[qt] = *reinterpret_cast<const s16x8*>(qpl + tq + (qt * 64 + lane) * 8);
        kf[qt] = *reinterpret_cast<const s16x8*>(kpl + tq + (qt * 64 + lane) * 8);
    }

    // S^T tiles: lane -> S[q = qt*16+l15][k = kt*16+lc*4+r]
    f32x4 st[4][4];
    #pragma unroll
    for (int kt = 0; kt < 4; ++kt)
        #pragma unroll
        for (int qt = 0; qt < 4; ++qt) {
            st[kt][qt] = (f32x4){0.f, 0.f, 0.f, 0.f};
            MFMA_BF16(st[kt][qt], kf[kt], qf[qt]);
        }

    // + rel-pos bias + shift mask + k-padding: vectorized f32x4 table loads
    const int wib = win & 255;
    const int cls = (((wib >> 4) == 15) ? 2 : 0) + (((wib & 15) == 15) ? 1 : 0);
    const float* tb = tbl + ((h * 4 + cls) << 12);
    #pragma unroll
    for (int kt = 0; kt < 4; ++kt)
        #pragma unroll
        for (int qt = 0; qt < 4; ++qt) {
            f32x4 tv = *reinterpret_cast<const f32x4*>(tb + kt * 1024 + qt * 256 + lane * 4);
            st[kt][qt] += tv;
        }

    // softmax per q-column (reduce across lc via xor16/xor32; rest lane-local)
    float inv[4];
    #pragma unroll
    for (int qt = 0; qt < 4; ++qt) {
        float mx = st[0][qt][0];
        #pragma unroll
        for (int kt = 0; kt < 4; ++kt)
            #pragma unroll
            for (int r = 0; r < 4; ++r) mx = fmaxf(mx, st[kt][qt][r]);
        mx = fmaxf(mx, __shfl_xor(mx, 16));
        mx = fmaxf(mx, __shfl_xor(mx, 32));
        float sum = 0.f;
        #pragma unroll
        for (int kt = 0; kt < 4; ++kt)
            #pragma unroll
            for (int r = 0; r < 4; ++r) {
                float e = __expf(st[kt][qt][r] - mx);
                st[kt][qt][r] = e; sum += e;
            }
        sum += __shfl_xor(sum, 16);
        sum += __shfl_xor(sum, 32);
        inv[qt] = 1.0f / sum;
    }

    // V loads deferred past softmax (lower peak VGPR)
    s16x8 vf[2][2];
    #pragma unroll
    for (int s = 0; s < 2; ++s)
        #pragma unroll
        for (int ni = 0; ni < 2; ++ni)
            vf[s][ni] = *reinterpret_cast<const s16x8*>(vpl + tq + ((s * 2 + ni) * 64 + lane) * 8);

    // P -> bf16, regroup D-layout (k = kt*16+lc*4+r) into A-frags (k = s*32+lc*8+j) via LDS
    #pragma unroll
    for (int kt = 0; kt < 4; ++kt)
        #pragma unroll
        for (int qt = 0; qt < 4; ++qt) {
            float p0 = st[kt][qt][0] * inv[qt], p1 = st[kt][qt][1] * inv[qt];
            float p2 = st[kt][qt][2] * inv[qt], p3 = st[kt][qt][3] * inv[qt];
            unsigned pk01 = (unsigned)bfh(p0) | ((unsigned)bfh(p1) << 16);
            unsigned pk23 = (unsigned)bfh(p2) | ((unsigned)bfh(p3) << 16);
            int tl = ((kt & 1) * 2 + (lc >> 1)) * 16 + l15;
            int base = (((kt >> 1) * 4 + qt) * 64 + tl) * 4 + (lc & 1) * 2;
            FR[base] = pk01; FR[base + 1] = pk23;
        }
    __syncthreads();
    s16x8 pa[2][4];
    #pragma unroll
    for (int s = 0; s < 2; ++s)
        #pragma unroll
        for (int qt = 0; qt < 4; ++qt)
            pa[s][qt] = *reinterpret_cast<const s16x8*>(&FR[((s * 4 + qt) * 64 + lane) * 4]);

    // O = P*V : lane -> O[q = qt*16+lc*4+r][d = ni*16+l15]
    f32x4 o[4][2];
    #pragma unroll
    for (int qt = 0; qt < 4; ++qt)
        #pragma unroll
        for (int ni = 0; ni < 2; ++ni) o[qt][ni] = (f32x4){0.f, 0.f, 0.f, 0.f};
    #pragma unroll
    for (int s = 0; s < 2; ++s)
        #pragma unroll
        for (int qt = 0; qt < 4; ++qt)
            #pragma unroll
            for (int ni = 0; ni < 2; ++ni)
                MFMA_BF16(o[qt][ni], pa[s][qt], vf[s][ni]);

    // write O as bf16 hi/lo planes (proj A-source; identical values to fp32-then-split)
    const size_t obase = (size_t)win * NTOK * CC + h * HD;
    #pragma unroll
    for (int qt = 0; qt < 4; ++qt)
        #pragma unroll
        for (int r = 0; r < 4; ++r) {
            int qrow = qt * 16 + lc * 4 + r;
            if (qrow < NTOK) {
                #pragma unroll
                for (int ni = 0; ni < 2; ++ni) {
                    size_t off = obase + (size_t)qrow * CC + ni * 16 + l15;
                    float val = o[qt][ni][r];
                    unsigned short hh = bfh(val);
                    oh[off] = hh;
                    ol[off] = bfh(val - bff(hh));
                }
            }
        }
}

// ---------------- launcher ----------------
extern "C" void kernel_launch(void* const* d_in, const int* in_sizes, int n_in,
                              void* d_out, int out_size, void* d_ws, size_t ws_size,
                              hipStream_t stream) {
    const float* x     = (const float*)d_in[0];
    const float* qkvw  = (const float*)d_in[1];
    const float* qkvb  = (const float*)d_in[2];
    const float* projw = (const float*)d_in[3];
    const float* projb = (const float*)d_in[4];
    const float* relb  = (const float*)d_in[5];

    char* ws = (char*)d_ws;
    short* qpl = (short*)ws;                                   // 3 x 100,663,296 B
    short* kpl = qpl + PLANE_U16;
    short* vpl = kpl + PLANE_U16;
    unsigned short* oh = (unsigned short*)(vpl + PLANE_U16);   // 4 x 77,070,336 B
    unsigned short* ol = oh + (size_t)NX;
    unsigned short* xh = ol + (size_t)NX;
    unsigned short* xl = xh + (size_t)NX;
    short* wqh  = (short*)(xl + (size_t)NX);                   // weights + table ~983 KB
    short* wql  = wqh + (size_t)WQ_SLOTS * 8;
    short* wph  = wql + (size_t)WQ_SLOTS * 8;
    short* wpl_ = wph + (size_t)WP_SLOTS * 8;
    float* tbl  = (float*)(wpl_ + (size_t)WP_SLOTS * 8);
    // total ws: 611,254,272 B (round-1 proved >= 616 MB available)

    xsplit<<<2048, 256, 0, stream>>>(x, xh, xl);
    prep<<<456, 256, 0, stream>>>(qkvw, projw, relb, wqh, wql, wph, wpl_, tbl);
    gemm_swapped<0><<<4704, 256, 0, stream>>>(xh, xl, wqh, wql, qkvb, qpl, kpl, vpl, nullptr);
    attn<<<dim3(TOTWIN, NHEAD), 64, 0, stream>>>(qpl, kpl, vpl, tbl, oh, ol);
    gemm_swapped<1><<<1568, 256, 0, stream>>>(oh, ol, wph, wpl_, projb,
                                              nullptr, nullptr, nullptr, (float*)d_out);
}